// Round 20
// baseline (295.831 us; speedup 1.0000x reference)
//
#include <hip/hip_runtime.h>

// ---------------------------------------------------------------------------
// Problem constants (from reference)
// ---------------------------------------------------------------------------
constexpr int H = 2, C = 32, HC = 64;
constexpr int NB = 128, TPER = 1024;
constexpr int NTASKS = NB * TPER;      // 131072
constexpr int NDATA = 65536;
constexpr int EE = 1048576;
constexpr int NDEV = 4;
constexpr int TASK_D = 12, DATA_D = 5, DEV_D = 12, EDGE_D = 3;
constexpr int EMB = 2 * C + TASK_D;    // 76
constexpr int HEAD_IN = 2 * EMB + NDEV * DEV_D; // 200
constexpr int ND2 = 2 * NTASKS;        // unified destination space (2^18)

constexpr int PSLICES = 256;                      // slices over unified 2*EE
constexpr int PSLICE_LEN = 2 * EE / PSLICES;      // 8192 edges per slice
constexpr int CAP = 32;                           // bucket capacity (Poisson(8): P(>=32)~1e-10)
constexpr int SCAT_BLOCKS = PSLICES * 8;          // 2048 (rr = b&7 XCD-aligned)
constexpr int PACK_BLOCKS = EE / 256;             // 4096
constexpr int PROJ_BLOCKS = NTASKS / 16;          // 8192 (4 waves x 4 rows)

// DPP partial sums (VALU pipe, no LDS). sum8: within 8-lane subgroup.
template <int CTRL>
__device__ __forceinline__ float dpp_addstep(float v) {
    int t = __builtin_amdgcn_update_dpp(0, __float_as_int(v), CTRL, 0xF, 0xF, true);
    return v + __int_as_float(t);
}
__device__ __forceinline__ float sum8(float v) {
    v = dpp_addstep<0xB1>(v);    // xor1 (quad perm)
    v = dpp_addstep<0x4E>(v);    // xor2 (quad perm)
    v = dpp_addstep<0x141>(v);   // row_half_mirror == xor4 once quads uniform
    return v;
}
__device__ __forceinline__ float sum16(float v) {
    v = sum8(v);
    v = dpp_addstep<0x140>(v);   // row_mirror == xor8 once 8-groups uniform
    return v;
}

// ---------------------------------------------------------------------------
// prep: heterogeneous blocks — scatter + pack + proj co-scheduled (r19 win).
// ---------------------------------------------------------------------------
__global__ __launch_bounds__(256) void prep_kernel(
        const int* __restrict__ ei_dt, const int* __restrict__ ei_tt,
        int* __restrict__ cnt, int* __restrict__ bucket,
        const float* __restrict__ data_x, const float* __restrict__ ea,
        float4* __restrict__ epk,
        const float* __restrict__ tx, const float* __restrict__ Wl2,
        const float* __restrict__ bl2, float* __restrict__ xlt2) {
    int b = blockIdx.x;
    if (b < SCAT_BLOCKS) {
        int rr = b & 7;
        int slice = b >> 3;
        int base = slice * PSLICE_LEN;
        bool isc1 = base < EE;
        int dlo = (rr << 14) + (isc1 ? 0 : NTASKS);
        int dhi = dlo + (1 << 14);
        if (isc1) {
            for (int i = threadIdx.x; i < PSLICE_LEN; i += 256) {
                int e = base + i;
                int d = ei_dt[EE + e];
                if (d >= dlo && d < dhi) {
                    int pos = atomicAdd(&cnt[d], 1);
                    if (pos < CAP) bucket[((size_t)pos << 18) + d] = e;
                }
            }
        } else {
            for (int i = threadIdx.x; i < PSLICE_LEN; i += 256) {
                int ee = base - EE + i;
                int d = NTASKS + ei_tt[EE + ee];
                if (d >= dlo && d < dhi) {
                    int pos = atomicAdd(&cnt[d], 1);
                    if (pos < CAP) bucket[((size_t)pos << 18) + d] = ei_tt[ee];
                }
            }
        }
    } else if (b < SCAT_BLOCKS + PACK_BLOCKS) {
        int e = (b - SCAT_BLOCKS) * 256 + threadIdx.x;   // 0 .. EE
        int s = ei_dt[e];
        const float* dp = data_x + (size_t)s * 5;
        float d0 = dp[0], d1 = dp[1], d2 = dp[2], d3 = dp[3], d4 = dp[4];
        float a0 = ea[(size_t)e * 3 + 0];
        float a1 = ea[(size_t)e * 3 + 1];
        float a2 = ea[(size_t)e * 3 + 2];
        epk[(size_t)e * 2 + 0] = make_float4(d0, d1, d2, d3);
        epk[(size_t)e * 2 + 1] = make_float4(d4, a0, a1, a2);
    } else {
        int wave = ((b - SCAT_BLOCKS - PACK_BLOCKS) * 256 + threadIdx.x) >> 6;
        int lane = threadIdx.x & 63;
        float w[12];
#pragma unroll
        for (int k = 0; k < 12; ++k) w[k] = Wl2[k * 64 + lane];
        float bv = bl2[lane];
#pragma unroll
        for (int r = 0; r < 4; ++r) {
            int row = wave * 4 + r;      // < NTASKS by grid construction
            const float4* xp = (const float4*)(tx + (size_t)row * 12);
            float4 x0 = xp[0], x1 = xp[1], x2 = xp[2];
            float xf[12] = { x0.x, x0.y, x0.z, x0.w, x1.x, x1.y, x1.z, x1.w,
                             x2.x, x2.y, x2.z, x2.w };
            float a = bv;
#pragma unroll
            for (int k = 0; k < 12; ++k) a = fmaf(xf[k], w[k], a);
            xlt2[(size_t)row * 64 + lane] = a;
        }
    }
}

// ---------------------------------------------------------------------------
// GATv2 body: 4 dsts per wave (one per 16-lane group); lane = grp*16+u holds
// channels 4u..4u+3. Bucket transposed: slot p of dst t at bucket[(p<<18)+t].
// conv1 (HAS_EA): random 32B epk record/edge, xl on the fly. conv2: 16B/lane
// projected-table row gathers. (Same code as r16/r19 gat, t passed in.)
// ---------------------------------------------------------------------------
template <bool HAS_EA>
__device__ __forceinline__ void gat_body(
        int t, int u,
        const int* __restrict__ bucket, const int* __restrict__ cnt,
        const float4* __restrict__ epk,
        const float* __restrict__ Wl, const float* __restrict__ bl,
        const float* __restrict__ We,
        const float* __restrict__ xlt,
        const float* __restrict__ Wr, const float* __restrict__ br,
        const float* __restrict__ att,
        const float* __restrict__ tx,
        const float* __restrict__ Wres, const float* __restrict__ bias,
        const float* __restrict__ g, const float* __restrict__ bln,
        float* __restrict__ out) {
    float4 att4 = ((const float4*)att)[u];
    float4 we0, we1, we2, wl0, wl1, wl2, wl3, wl4, bl4;
    if (HAS_EA) {
        we0 = ((const float4*)We)[u];
        we1 = ((const float4*)(We + 64))[u];
        we2 = ((const float4*)(We + 128))[u];
        wl0 = ((const float4*)(Wl + 0 * 64))[u];
        wl1 = ((const float4*)(Wl + 1 * 64))[u];
        wl2 = ((const float4*)(Wl + 2 * 64))[u];
        wl3 = ((const float4*)(Wl + 3 * 64))[u];
        wl4 = ((const float4*)(Wl + 4 * 64))[u];
        bl4 = ((const float4*)bl)[u];
    }

    // on-the-fly xr from the tasks_x row (row reloaded in the epilogue)
    const float4* tp = (const float4*)(tx + (size_t)t * 12);
    float4 xr4 = ((const float4*)br)[u];
    {
        float4 t0 = tp[0], t1 = tp[1], t2 = tp[2];
        float tf[12] = { t0.x, t0.y, t0.z, t0.w, t1.x, t1.y, t1.z, t1.w,
                         t2.x, t2.y, t2.z, t2.w };
#pragma unroll
        for (int k = 0; k < 12; ++k) {
            float4 w = ((const float4*)(Wr + k * 64))[u];
            xr4.x = fmaf(tf[k], w.x, xr4.x);
            xr4.y = fmaf(tf[k], w.y, xr4.y);
            xr4.z = fmaf(tf[k], w.z, xr4.z);
            xr4.w = fmaf(tf[k], w.w, xr4.w);
        }
    }

    int len = min(cnt[t], CAP);        // per-group; loop below is group-divergent
    float den = 0.f;
    float4 accv = make_float4(0.f, 0.f, 0.f, 0.f);

    for (int i0 = 0; i0 < len; i0 += 4) {
        int cur[4];
#pragma unroll
        for (int j = 0; j < 4; ++j) {
            int slot = (i0 + j < len) ? (i0 + j) : 0;    // slot 0 valid (len > 0)
            cur[j] = bucket[((size_t)slot << 18) + t];
        }
        float4 gv[4];
        float p[4];
        if (HAS_EA) {
            float4 e0[4], e1[4];
#pragma unroll
            for (int j = 0; j < 4; ++j) {
                e0[j] = epk[(size_t)cur[j] * 2 + 0];     // one 64B line per edge
                e1[j] = epk[(size_t)cur[j] * 2 + 1];
            }
#pragma unroll
            for (int j = 0; j < 4; ++j) {
                float4 xl4 = bl4;
                xl4.x = fmaf(e0[j].x, wl0.x, xl4.x); xl4.y = fmaf(e0[j].x, wl0.y, xl4.y);
                xl4.z = fmaf(e0[j].x, wl0.z, xl4.z); xl4.w = fmaf(e0[j].x, wl0.w, xl4.w);
                xl4.x = fmaf(e0[j].y, wl1.x, xl4.x); xl4.y = fmaf(e0[j].y, wl1.y, xl4.y);
                xl4.z = fmaf(e0[j].y, wl1.z, xl4.z); xl4.w = fmaf(e0[j].y, wl1.w, xl4.w);
                xl4.x = fmaf(e0[j].z, wl2.x, xl4.x); xl4.y = fmaf(e0[j].z, wl2.y, xl4.y);
                xl4.z = fmaf(e0[j].z, wl2.z, xl4.z); xl4.w = fmaf(e0[j].z, wl2.w, xl4.w);
                xl4.x = fmaf(e0[j].w, wl3.x, xl4.x); xl4.y = fmaf(e0[j].w, wl3.y, xl4.y);
                xl4.z = fmaf(e0[j].w, wl3.z, xl4.z); xl4.w = fmaf(e0[j].w, wl3.w, xl4.w);
                xl4.x = fmaf(e1[j].x, wl4.x, xl4.x); xl4.y = fmaf(e1[j].x, wl4.y, xl4.y);
                xl4.z = fmaf(e1[j].x, wl4.z, xl4.z); xl4.w = fmaf(e1[j].x, wl4.w, xl4.w);
                gv[j] = xl4;
                float4 m4;
                m4.x = xl4.x + xr4.x; m4.y = xl4.y + xr4.y;
                m4.z = xl4.z + xr4.z; m4.w = xl4.w + xr4.w;
                m4.x = fmaf(e1[j].y, we0.x, fmaf(e1[j].z, we1.x, fmaf(e1[j].w, we2.x, m4.x)));
                m4.y = fmaf(e1[j].y, we0.y, fmaf(e1[j].z, we1.y, fmaf(e1[j].w, we2.y, m4.y)));
                m4.z = fmaf(e1[j].y, we0.z, fmaf(e1[j].z, we1.z, fmaf(e1[j].w, we2.z, m4.z)));
                m4.w = fmaf(e1[j].y, we0.w, fmaf(e1[j].z, we1.w, fmaf(e1[j].w, we2.w, m4.w)));
                float lx = fmaxf(m4.x, 0.f) + 0.2f * fminf(m4.x, 0.f);
                float ly = fmaxf(m4.y, 0.f) + 0.2f * fminf(m4.y, 0.f);
                float lz = fmaxf(m4.z, 0.f) + 0.2f * fminf(m4.z, 0.f);
                float lw = fmaxf(m4.w, 0.f) + 0.2f * fminf(m4.w, 0.f);
                p[j] = fmaf(att4.x, lx, fmaf(att4.y, ly, fmaf(att4.z, lz, att4.w * lw)));
            }
        } else {
#pragma unroll
            for (int j = 0; j < 4; ++j)                  // 16B/lane row gathers
                gv[j] = ((const float4*)(xlt + (size_t)cur[j] * 64))[u];
#pragma unroll
            for (int j = 0; j < 4; ++j) {
                float4 m4;
                m4.x = gv[j].x + xr4.x; m4.y = gv[j].y + xr4.y;
                m4.z = gv[j].z + xr4.z; m4.w = gv[j].w + xr4.w;
                float lx = fmaxf(m4.x, 0.f) + 0.2f * fminf(m4.x, 0.f);
                float ly = fmaxf(m4.y, 0.f) + 0.2f * fminf(m4.y, 0.f);
                float lz = fmaxf(m4.z, 0.f) + 0.2f * fminf(m4.z, 0.f);
                float lw = fmaxf(m4.w, 0.f) + 0.2f * fminf(m4.w, 0.f);
                p[j] = fmaf(att4.x, lx, fmaf(att4.y, ly, fmaf(att4.z, lz, att4.w * lw)));
            }
        }
        // per-head logits: sum over the 8-lane subgroup (head-major layout)
#pragma unroll
        for (int j = 0; j < 4; ++j) p[j] = sum8(p[j]);
#pragma unroll
        for (int j = 0; j < 4; ++j) {
            float ex = __expf(p[j]);
            ex = (i0 + j < len) ? ex : 0.f;          // mask tail
            den += ex;
            accv.x = fmaf(ex, gv[j].x, accv.x);
            accv.y = fmaf(ex, gv[j].y, accv.y);
            accv.z = fmaf(ex, gv[j].z, accv.z);
            accv.w = fmaf(ex, gv[j].w, accv.w);
        }
    }

    // finalize: per-head normalize, then head mean via xor8 (lane u <-> u^8)
    float inv = 1.0f / (den + 1e-16f);
    float4 ox = make_float4(accv.x * inv, accv.y * inv, accv.z * inv, accv.w * inv);
    float4 oo;
    oo.x = __shfl_xor(ox.x, 8, 64);
    oo.y = __shfl_xor(ox.y, 8, 64);
    oo.z = __shfl_xor(ox.z, 8, 64);
    oo.w = __shfl_xor(ox.w, 8, 64);
    float4 hm = make_float4(0.5f * (ox.x + oo.x), 0.5f * (ox.y + oo.y),
                            0.5f * (ox.z + oo.z), 0.5f * (ox.w + oo.w));

    // residual + LayerNorm + leaky(0.01); reload the tasks_x row here
    float4 r0 = tp[0], r1 = tp[1], r2 = tp[2];
    float tf[12] = { r0.x, r0.y, r0.z, r0.w, r1.x, r1.y, r1.z, r1.w,
                     r2.x, r2.y, r2.z, r2.w };
    int u8 = u & 7;
    float4 bias4 = ((const float4*)bias)[u8];
    float4 v4 = make_float4(hm.x + bias4.x, hm.y + bias4.y,
                            hm.z + bias4.z, hm.w + bias4.w);
#pragma unroll
    for (int k = 0; k < 12; ++k) {
        float4 w = ((const float4*)(Wres + k * 32))[u8];
        v4.x = fmaf(tf[k], w.x, v4.x);
        v4.y = fmaf(tf[k], w.y, v4.y);
        v4.z = fmaf(tf[k], w.z, v4.z);
        v4.w = fmaf(tf[k], w.w, v4.w);
    }
    float loc = v4.x + v4.y + v4.z + v4.w;
    float mean = sum16(loc) * (1.0f / 64.0f);    // lanes u and u^8 duplicate
    float4 dd = make_float4(v4.x - mean, v4.y - mean, v4.z - mean, v4.w - mean);
    float q2l = dd.x * dd.x + dd.y * dd.y + dd.z * dd.z + dd.w * dd.w;
    float var = sum16(q2l) * (1.0f / 64.0f);
    float rs = rsqrtf(var + 1e-5f);
    float4 g4 = ((const float4*)g)[u8];
    float4 b4 = ((const float4*)bln)[u8];
    float4 y;
    y.x = dd.x * rs * g4.x + b4.x;  y.x = (y.x >= 0.f ? y.x : 0.01f * y.x);
    y.y = dd.y * rs * g4.y + b4.y;  y.y = (y.y >= 0.f ? y.y : 0.01f * y.y);
    y.z = dd.z * rs * g4.z + b4.z;  y.z = (y.z >= 0.f ? y.z : 0.01f * y.z);
    y.w = dd.w * rs * g4.w + b4.w;  y.w = (y.w >= 0.f ? y.w : 0.01f * y.w);
    if (u < 8) *((float4*)(out + (size_t)t * 32 + 4 * u8)) = y;
}

// ---------------------------------------------------------------------------
// Both convs in ONE launch, block-interleaved (conv = (b>>3)&1, rr = b&7 so
// XCD alignment with the scatter partition is preserved). Register-symmetric
// classes (~64-68 VGPR each) -> no occupancy poisoning (cf. r10 failure).
// conv1 stalls (random epk records) are filled by conv2 issue (xlt rows) and
// vice versa — the same backfill mechanism that paid in prep (r19).
// ---------------------------------------------------------------------------
__global__ __launch_bounds__(256) void gat_both_kernel(
        const int* __restrict__ bucket, const int* __restrict__ cnt,
        const float4* __restrict__ epk,
        const float* __restrict__ c1_Wl, const float* __restrict__ c1_bl,
        const float* __restrict__ c1_We, const float* __restrict__ c1_Wr,
        const float* __restrict__ c1_br, const float* __restrict__ c1_att,
        const float* __restrict__ c1_Wres, const float* __restrict__ c1_bias,
        const float* __restrict__ ln1_g, const float* __restrict__ ln1_b,
        const float* __restrict__ xlt2, const float* __restrict__ c2_Wr,
        const float* __restrict__ c2_br, const float* __restrict__ c2_att,
        const float* __restrict__ c2_Wres, const float* __restrict__ c2_bias,
        const float* __restrict__ ln2_g, const float* __restrict__ ln2_b,
        const float* __restrict__ tx,
        float* __restrict__ dft, float* __restrict__ tft) {
    int widx = threadIdx.x >> 6;
    int lane = threadIdx.x & 63;
    int grp = lane >> 4;
    int u = lane & 15;
    int b = blockIdx.x;
    int rr = b & 7;                    // XCD-aligned dst range
    int v = b >> 3;
    bool isc1 = (v & 1) == 0;          // fine-grained conv interleave
    int q = v >> 1;                    // 0..1023
    int t = (rr << 14) + q * 16 + widx * 4 + grp;

    if (isc1) {
        gat_body<true>(t, u, bucket, cnt, epk, c1_Wl, c1_bl, c1_We, nullptr,
                       c1_Wr, c1_br, c1_att, tx, c1_Wres, c1_bias, ln1_g, ln1_b, dft);
    } else {
        gat_body<false>(t, u, bucket + NTASKS, cnt + NTASKS, nullptr,
                        nullptr, nullptr, nullptr, xlt2,
                        c2_Wr, c2_br, c2_att, tx, c2_Wres, c2_bias, ln2_g, ln2_b, tft);
    }
}

// ---------------------------------------------------------------------------
// pool: per-(graph,chunk) partial sums, no atomics, no memset needed.
// ---------------------------------------------------------------------------
__global__ void pool_kernel(const float* __restrict__ tx, const float* __restrict__ dft,
                            const float* __restrict__ tft, float* __restrict__ glob16) {
    int g = blockIdx.x >> 4;
    int ch = blockIdx.x & 15;
    int j = threadIdx.x;
    if (j >= EMB) return;
    int base = g * TPER + ch * 64;
    float s = 0.0f;
    for (int t = 0; t < 64; ++t) {
        int task = base + t;
        float v;
        if (j < 12)      v = tx[(size_t)task * 12 + j];
        else if (j < 44) v = dft[(size_t)task * 32 + (j - 12)];
        else             v = tft[(size_t)task * 32 + (j - 44)];
        s += v;
    }
    glob16[(size_t)blockIdx.x * EMB + j] = s;
}

// ---------------------------------------------------------------------------
// head: per-graph cand/glob/dev concat -> [200] @ h1_W -> LN -> leaky -> h2
// ---------------------------------------------------------------------------
__global__ void head_kernel(const float* __restrict__ tx, const float* __restrict__ dft,
                            const float* __restrict__ tft, const float* __restrict__ glob16,
                            const float* __restrict__ devx, const float* __restrict__ counts,
                            const int* __restrict__ ptrv,
                            const float* __restrict__ h1_W, const float* __restrict__ h1_b,
                            const float* __restrict__ hln_g, const float* __restrict__ hln_b,
                            const float* __restrict__ h2_W, const float* __restrict__ h2_b,
                            float* __restrict__ out) {
    __shared__ float xs[HEAD_IN];
    __shared__ float ys[32];
    int b = blockIdx.x;
    int l = threadIdx.x; // 64 threads
    int p = ptrv[b];
    float inv = 1.0f / fmaxf(counts[b], 1.0f);
    for (int j = l; j < HEAD_IN; j += 64) {
        float v;
        if (j < 12)       v = tx[(size_t)p * 12 + j];
        else if (j < 44)  v = dft[(size_t)p * 32 + (j - 12)];
        else if (j < 76)  v = tft[(size_t)p * 32 + (j - 44)];
        else if (j < 152) {
            float s = 0.f;
#pragma unroll
            for (int c = 0; c < 16; ++c)
                s += glob16[(size_t)(b * 16 + c) * EMB + (j - 76)];
            v = s * inv;
        }
        else              v = devx[b * (NDEV * DEV_D) + (j - 152)];
        xs[j] = v;
    }
    __syncthreads();
    if (l < 32) {
        float h = h1_b[l];
        for (int k = 0; k < HEAD_IN; ++k)
            h += xs[k] * h1_W[k * 32 + l];
        float s = h;
#pragma unroll
        for (int off = 16; off; off >>= 1) s += __shfl_xor(s, off, 64);
        float mean = s * (1.0f / 32.0f);
        float dd = h - mean;
        float q = dd * dd;
#pragma unroll
        for (int off = 16; off; off >>= 1) q += __shfl_xor(q, off, 64);
        float var = q * (1.0f / 32.0f);
        float y = dd * rsqrtf(var + 1e-5f) * hln_g[l] + hln_b[l];
        ys[l] = (y >= 0.0f ? y : 0.01f * y);
    }
    __syncthreads();
    if (l < NDEV - 1) {
        float o = h2_b[l];
        for (int c = 0; c < 32; ++c)
            o += ys[c] * h2_W[c * 3 + l];
        out[b * (NDEV - 1) + l] = o;
    }
}

// ---------------------------------------------------------------------------
// launch
// ---------------------------------------------------------------------------
extern "C" void kernel_launch(void* const* d_in, const int* in_sizes, int n_in,
                              void* d_out, int out_size, void* d_ws, size_t ws_size,
                              hipStream_t stream) {
    const float* tasks_x   = (const float*)d_in[0];
    const float* data_x    = (const float*)d_in[1];
    const float* devices_x = (const float*)d_in[2];
    const int*   ei_dt     = (const int*)d_in[3];
    const float* ea_dt     = (const float*)d_in[4];
    const int*   ei_tt     = (const int*)d_in[5];
    // d_in[6] = batch (unused: graphs are contiguous TPER chunks)
    const int*   ptrv      = (const int*)d_in[7];
    const float* counts    = (const float*)d_in[8];
    const float* c1_Wl   = (const float*)d_in[9];
    const float* c1_bl   = (const float*)d_in[10];
    const float* c1_Wr   = (const float*)d_in[11];
    const float* c1_br   = (const float*)d_in[12];
    const float* c1_We   = (const float*)d_in[13];
    const float* c1_att  = (const float*)d_in[14];
    const float* c1_Wres = (const float*)d_in[15];
    const float* c1_bias = (const float*)d_in[16];
    const float* c2_Wl   = (const float*)d_in[17];
    const float* c2_bl   = (const float*)d_in[18];
    const float* c2_Wr   = (const float*)d_in[19];
    const float* c2_br   = (const float*)d_in[20];
    const float* c2_att  = (const float*)d_in[21];
    const float* c2_Wres = (const float*)d_in[22];
    const float* c2_bias = (const float*)d_in[23];
    const float* ln1_g = (const float*)d_in[24];
    const float* ln1_b = (const float*)d_in[25];
    const float* ln2_g = (const float*)d_in[26];
    const float* ln2_b = (const float*)d_in[27];
    const float* h1_W  = (const float*)d_in[28];
    const float* h1_b  = (const float*)d_in[29];
    const float* hln_g = (const float*)d_in[30];
    const float* hln_b = (const float*)d_in[31];
    const float* h2_W  = (const float*)d_in[32];
    const float* h2_b  = (const float*)d_in[33];
    float* out = (float*)d_out;

    // workspace layout (~135MB)
    char* ws = (char*)d_ws;
    size_t off = 0;
    auto alloc = [&](size_t bytes) -> void* {
        void* p = (void*)(ws + off);
        off += (bytes + 255) & ~(size_t)255;
        return p;
    };
    int*    cnt     = (int*)alloc((size_t)ND2 * 4);            // 1MB
    int*    bucket  = (int*)alloc((size_t)ND2 * CAP * 4);      // 33.5MB (transposed)
    float4* epk     = (float4*)alloc((size_t)EE * 32);         // 33.5MB
    float*  xlt2    = (float*)alloc((size_t)NTASKS * 64 * 4);  // 33.5MB
    float*  dft     = (float*)alloc((size_t)NTASKS * 32 * 4);  // 16.8MB
    float*  tft     = (float*)alloc((size_t)NTASKS * 32 * 4);  // 16.8MB
    float*  glob16  = (float*)alloc((size_t)NB * 16 * EMB * 4);
    if (off > ws_size) return;

    const int BLK = 256;

    // ---- prep: scatter + conv1 pack + conv2 xl table, co-scheduled ----
    hipMemsetAsync(cnt, 0, (size_t)ND2 * 4, stream);
    prep_kernel<<<SCAT_BLOCKS + PACK_BLOCKS + PROJ_BLOCKS, BLK, 0, stream>>>(
        ei_dt, ei_tt, cnt, bucket, data_x, ea_dt, epk, tasks_x, c2_Wl, c2_bl, xlt2);

    // ---- both convs in one launch (block-interleaved, XCD-aligned) ----
    gat_both_kernel<<<2 * NTASKS / 16, BLK, 0, stream>>>(
        bucket, cnt, epk,
        c1_Wl, c1_bl, c1_We, c1_Wr, c1_br, c1_att, c1_Wres, c1_bias, ln1_g, ln1_b,
        xlt2, c2_Wr, c2_br, c2_att, c2_Wres, c2_bias, ln2_g, ln2_b,
        tasks_x, dft, tft);

    // ---- pooling + head ----
    pool_kernel<<<NB * 16, 128, 0, stream>>>(tasks_x, dft, tft, glob16);
    head_kernel<<<NB, 64, 0, stream>>>(tasks_x, dft, tft, glob16, devices_x, counts, ptrv,
                                       h1_W, h1_b, hln_g, hln_b, h2_W, h2_b, out);
}

// Round 21
// 273.034 us; speedup vs baseline: 1.0835x; 1.0835x over previous
//
#include <hip/hip_runtime.h>

// ---------------------------------------------------------------------------
// Problem constants (from reference)
// ---------------------------------------------------------------------------
constexpr int H = 2, C = 32, HC = 64;
constexpr int NB = 128, TPER = 1024;
constexpr int NTASKS = NB * TPER;      // 131072
constexpr int NDATA = 65536;
constexpr int EE = 1048576;
constexpr int NDEV = 4;
constexpr int TASK_D = 12, DATA_D = 5, DEV_D = 12, EDGE_D = 3;
constexpr int EMB = 2 * C + TASK_D;    // 76
constexpr int HEAD_IN = 2 * EMB + NDEV * DEV_D; // 200
constexpr int ND2 = 2 * NTASKS;        // unified destination space (2^18)

constexpr int PSLICES = 256;                      // slices over unified 2*EE
constexpr int PSLICE_LEN = 2 * EE / PSLICES;      // 8192 edges per slice
constexpr int CAP = 32;                           // bucket capacity (Poisson(8): P(>=32)~1e-10)
constexpr int SCAT_BLOCKS = PSLICES * 8;          // 2048 (rr = b&7 XCD-aligned)
constexpr int PACK_BLOCKS = EE / 256;             // 4096
constexpr int PROJ_BLOCKS = NTASKS / 16;          // 8192 (4 waves x 4 rows)

// DPP partial sums (VALU pipe, no LDS). sum8: within 8-lane subgroup.
template <int CTRL>
__device__ __forceinline__ float dpp_addstep(float v) {
    int t = __builtin_amdgcn_update_dpp(0, __float_as_int(v), CTRL, 0xF, 0xF, true);
    return v + __int_as_float(t);
}
__device__ __forceinline__ float sum8(float v) {
    v = dpp_addstep<0xB1>(v);    // xor1 (quad perm)
    v = dpp_addstep<0x4E>(v);    // xor2 (quad perm)
    v = dpp_addstep<0x141>(v);   // row_half_mirror == xor4 once quads uniform
    return v;
}
__device__ __forceinline__ float sum16(float v) {
    v = sum8(v);
    v = dpp_addstep<0x140>(v);   // row_mirror == xor8 once 8-groups uniform
    return v;
}

// ---------------------------------------------------------------------------
// prep: heterogeneous blocks — three independent work classes co-scheduled so
// the scatter's latency/atomic stalls are backfilled by streaming pack/proj.
//  blocks [0, SCAT_BLOCKS): XCD-local partitioned bucket scatter
//    (transposed layout bucket[pos*ND2 + d]; rr = b&7 matches gat mapping)
//  blocks [+PACK_BLOCKS): conv1 record pack
//    epk[e] = {data_x[src[e]][0..4], ea[e][0..2]} (32B; data_x L2-resident)
//  blocks [+PROJ_BLOCKS): conv2 xl projection table
// Max VGPR across classes ~32 -> no occupancy poisoning (cf. r10/r20 failures).
// ---------------------------------------------------------------------------
__global__ __launch_bounds__(256) void prep_kernel(
        const int* __restrict__ ei_dt, const int* __restrict__ ei_tt,
        int* __restrict__ cnt, int* __restrict__ bucket,
        const float* __restrict__ data_x, const float* __restrict__ ea,
        float4* __restrict__ epk,
        const float* __restrict__ tx, const float* __restrict__ Wl2,
        const float* __restrict__ bl2, float* __restrict__ xlt2) {
    int b = blockIdx.x;
    if (b < SCAT_BLOCKS) {
        int rr = b & 7;
        int slice = b >> 3;
        int base = slice * PSLICE_LEN;
        bool isc1 = base < EE;
        int dlo = (rr << 14) + (isc1 ? 0 : NTASKS);
        int dhi = dlo + (1 << 14);
        if (isc1) {
            for (int i = threadIdx.x; i < PSLICE_LEN; i += 256) {
                int e = base + i;
                int d = ei_dt[EE + e];
                if (d >= dlo && d < dhi) {
                    int pos = atomicAdd(&cnt[d], 1);
                    if (pos < CAP) bucket[((size_t)pos << 18) + d] = e;
                }
            }
        } else {
            for (int i = threadIdx.x; i < PSLICE_LEN; i += 256) {
                int ee = base - EE + i;
                int d = NTASKS + ei_tt[EE + ee];
                if (d >= dlo && d < dhi) {
                    int pos = atomicAdd(&cnt[d], 1);
                    if (pos < CAP) bucket[((size_t)pos << 18) + d] = ei_tt[ee];
                }
            }
        }
    } else if (b < SCAT_BLOCKS + PACK_BLOCKS) {
        int e = (b - SCAT_BLOCKS) * 256 + threadIdx.x;   // 0 .. EE
        int s = ei_dt[e];
        const float* dp = data_x + (size_t)s * 5;
        float d0 = dp[0], d1 = dp[1], d2 = dp[2], d3 = dp[3], d4 = dp[4];
        float a0 = ea[(size_t)e * 3 + 0];
        float a1 = ea[(size_t)e * 3 + 1];
        float a2 = ea[(size_t)e * 3 + 2];
        epk[(size_t)e * 2 + 0] = make_float4(d0, d1, d2, d3);
        epk[(size_t)e * 2 + 1] = make_float4(d4, a0, a1, a2);
    } else {
        int wave = ((b - SCAT_BLOCKS - PACK_BLOCKS) * 256 + threadIdx.x) >> 6;
        int lane = threadIdx.x & 63;
        float w[12];
#pragma unroll
        for (int k = 0; k < 12; ++k) w[k] = Wl2[k * 64 + lane];
        float bv = bl2[lane];
#pragma unroll
        for (int r = 0; r < 4; ++r) {
            int row = wave * 4 + r;      // < NTASKS by grid construction
            const float4* xp = (const float4*)(tx + (size_t)row * 12);
            float4 x0 = xp[0], x1 = xp[1], x2 = xp[2];
            float xf[12] = { x0.x, x0.y, x0.z, x0.w, x1.x, x1.y, x1.z, x1.w,
                             x2.x, x2.y, x2.z, x2.w };
            float a = bv;
#pragma unroll
            for (int k = 0; k < 12; ++k) a = fmaf(xf[k], w[k], a);
            xlt2[(size_t)row * 64 + lane] = a;
        }
    }
}

// ---------------------------------------------------------------------------
// Fused GATv2 aggregation, 4 DESTINATIONS per wave (one per 16-lane group).
// Lane = grp*16 + u; lane holds channels (4u..4u+3) as float4 of grp's dst.
// Bucket (transposed): edge slot p of dst t at bucket[(p<<18) + t]; the 4
// groups of a wave read consecutive t -> plane lines shared across dsts.
// conv1 (HAS_EA): one random 32B epk record per edge, xl on the fly (5 dims).
// conv2: 16B/lane projected-table row gathers.
// ---------------------------------------------------------------------------
template <bool HAS_EA>
__global__ __launch_bounds__(256) void gat_gather4_kernel(
        const int* __restrict__ bucket,     // pre-offset: conv1 base / conv2 +NTASKS
        const int* __restrict__ cnt,        // pre-offset: conv1 base / conv2 +NTASKS
        const float4* __restrict__ epk,
        const float* __restrict__ Wl, const float* __restrict__ bl,
        const float* __restrict__ We,
        const float* __restrict__ xlt,      // conv2: [NTASKS,64] projected src table
        const float* __restrict__ Wr, const float* __restrict__ br,
        const float* __restrict__ att,
        const float* __restrict__ tx,       // tasks_x: on-the-fly xr + residual
        const float* __restrict__ Wres, const float* __restrict__ bias,
        const float* __restrict__ g, const float* __restrict__ bln,
        float* __restrict__ out) {
    int widx = threadIdx.x >> 6;       // wave in block: 0..3
    int lane = threadIdx.x & 63;
    int grp = lane >> 4;               // dst group 0..3
    int u = lane & 15;                 // lane in group; channels 4u..4u+3
    int rr = blockIdx.x & 7;           // dst range (XCD-aligned with scatter)
    int q = blockIdx.x >> 3;
    int t = (rr << 14) + q * 16 + widx * 4 + grp;   // this group's dst

    float4 att4 = ((const float4*)att)[u];
    float4 we0, we1, we2, wl0, wl1, wl2, wl3, wl4, bl4;
    if (HAS_EA) {
        we0 = ((const float4*)We)[u];
        we1 = ((const float4*)(We + 64))[u];
        we2 = ((const float4*)(We + 128))[u];
        wl0 = ((const float4*)(Wl + 0 * 64))[u];
        wl1 = ((const float4*)(Wl + 1 * 64))[u];
        wl2 = ((const float4*)(Wl + 2 * 64))[u];
        wl3 = ((const float4*)(Wl + 3 * 64))[u];
        wl4 = ((const float4*)(Wl + 4 * 64))[u];
        bl4 = ((const float4*)bl)[u];
    }

    // on-the-fly xr from the tasks_x row (row reloaded in the epilogue)
    const float4* tp = (const float4*)(tx + (size_t)t * 12);
    float4 xr4 = ((const float4*)br)[u];
    {
        float4 t0 = tp[0], t1 = tp[1], t2 = tp[2];
        float tf[12] = { t0.x, t0.y, t0.z, t0.w, t1.x, t1.y, t1.z, t1.w,
                         t2.x, t2.y, t2.z, t2.w };
#pragma unroll
        for (int k = 0; k < 12; ++k) {
            float4 w = ((const float4*)(Wr + k * 64))[u];
            xr4.x = fmaf(tf[k], w.x, xr4.x);
            xr4.y = fmaf(tf[k], w.y, xr4.y);
            xr4.z = fmaf(tf[k], w.z, xr4.z);
            xr4.w = fmaf(tf[k], w.w, xr4.w);
        }
    }

    int len = min(cnt[t], CAP);        // per-group; loop below is group-divergent
    float den = 0.f;
    float4 accv = make_float4(0.f, 0.f, 0.f, 0.f);

    for (int i0 = 0; i0 < len; i0 += 4) {
        int cur[4];
#pragma unroll
        for (int j = 0; j < 4; ++j) {
            int slot = (i0 + j < len) ? (i0 + j) : 0;    // slot 0 valid (len > 0)
            cur[j] = bucket[((size_t)slot << 18) + t];
        }
        float4 gv[4];
        float p[4];
        if (HAS_EA) {
            float4 e0[4], e1[4];
#pragma unroll
            for (int j = 0; j < 4; ++j) {
                e0[j] = epk[(size_t)cur[j] * 2 + 0];     // one 64B line per edge
                e1[j] = epk[(size_t)cur[j] * 2 + 1];
            }
#pragma unroll
            for (int j = 0; j < 4; ++j) {
                float4 xl4 = bl4;
                xl4.x = fmaf(e0[j].x, wl0.x, xl4.x); xl4.y = fmaf(e0[j].x, wl0.y, xl4.y);
                xl4.z = fmaf(e0[j].x, wl0.z, xl4.z); xl4.w = fmaf(e0[j].x, wl0.w, xl4.w);
                xl4.x = fmaf(e0[j].y, wl1.x, xl4.x); xl4.y = fmaf(e0[j].y, wl1.y, xl4.y);
                xl4.z = fmaf(e0[j].y, wl1.z, xl4.z); xl4.w = fmaf(e0[j].y, wl1.w, xl4.w);
                xl4.x = fmaf(e0[j].z, wl2.x, xl4.x); xl4.y = fmaf(e0[j].z, wl2.y, xl4.y);
                xl4.z = fmaf(e0[j].z, wl2.z, xl4.z); xl4.w = fmaf(e0[j].z, wl2.w, xl4.w);
                xl4.x = fmaf(e0[j].w, wl3.x, xl4.x); xl4.y = fmaf(e0[j].w, wl3.y, xl4.y);
                xl4.z = fmaf(e0[j].w, wl3.z, xl4.z); xl4.w = fmaf(e0[j].w, wl3.w, xl4.w);
                xl4.x = fmaf(e1[j].x, wl4.x, xl4.x); xl4.y = fmaf(e1[j].x, wl4.y, xl4.y);
                xl4.z = fmaf(e1[j].x, wl4.z, xl4.z); xl4.w = fmaf(e1[j].x, wl4.w, xl4.w);
                gv[j] = xl4;
                float4 m4;
                m4.x = xl4.x + xr4.x; m4.y = xl4.y + xr4.y;
                m4.z = xl4.z + xr4.z; m4.w = xl4.w + xr4.w;
                m4.x = fmaf(e1[j].y, we0.x, fmaf(e1[j].z, we1.x, fmaf(e1[j].w, we2.x, m4.x)));
                m4.y = fmaf(e1[j].y, we0.y, fmaf(e1[j].z, we1.y, fmaf(e1[j].w, we2.y, m4.y)));
                m4.z = fmaf(e1[j].y, we0.z, fmaf(e1[j].z, we1.z, fmaf(e1[j].w, we2.z, m4.z)));
                m4.w = fmaf(e1[j].y, we0.w, fmaf(e1[j].z, we1.w, fmaf(e1[j].w, we2.w, m4.w)));
                float lx = fmaxf(m4.x, 0.f) + 0.2f * fminf(m4.x, 0.f);
                float ly = fmaxf(m4.y, 0.f) + 0.2f * fminf(m4.y, 0.f);
                float lz = fmaxf(m4.z, 0.f) + 0.2f * fminf(m4.z, 0.f);
                float lw = fmaxf(m4.w, 0.f) + 0.2f * fminf(m4.w, 0.f);
                p[j] = fmaf(att4.x, lx, fmaf(att4.y, ly, fmaf(att4.z, lz, att4.w * lw)));
            }
        } else {
#pragma unroll
            for (int j = 0; j < 4; ++j)                  // 16B/lane row gathers
                gv[j] = ((const float4*)(xlt + (size_t)cur[j] * 64))[u];
#pragma unroll
            for (int j = 0; j < 4; ++j) {
                float4 m4;
                m4.x = gv[j].x + xr4.x; m4.y = gv[j].y + xr4.y;
                m4.z = gv[j].z + xr4.z; m4.w = gv[j].w + xr4.w;
                float lx = fmaxf(m4.x, 0.f) + 0.2f * fminf(m4.x, 0.f);
                float ly = fmaxf(m4.y, 0.f) + 0.2f * fminf(m4.y, 0.f);
                float lz = fmaxf(m4.z, 0.f) + 0.2f * fminf(m4.z, 0.f);
                float lw = fmaxf(m4.w, 0.f) + 0.2f * fminf(m4.w, 0.f);
                p[j] = fmaf(att4.x, lx, fmaf(att4.y, ly, fmaf(att4.z, lz, att4.w * lw)));
            }
        }
        // per-head logits: sum over the 8-lane subgroup (head-major layout)
#pragma unroll
        for (int j = 0; j < 4; ++j) p[j] = sum8(p[j]);
#pragma unroll
        for (int j = 0; j < 4; ++j) {
            float ex = __expf(p[j]);
            ex = (i0 + j < len) ? ex : 0.f;          // mask tail
            den += ex;
            accv.x = fmaf(ex, gv[j].x, accv.x);
            accv.y = fmaf(ex, gv[j].y, accv.y);
            accv.z = fmaf(ex, gv[j].z, accv.z);
            accv.w = fmaf(ex, gv[j].w, accv.w);
        }
    }

    // finalize: per-head normalize, then head mean via xor8 (lane u <-> u^8)
    float inv = 1.0f / (den + 1e-16f);
    float4 ox = make_float4(accv.x * inv, accv.y * inv, accv.z * inv, accv.w * inv);
    float4 oo;
    oo.x = __shfl_xor(ox.x, 8, 64);
    oo.y = __shfl_xor(ox.y, 8, 64);
    oo.z = __shfl_xor(ox.z, 8, 64);
    oo.w = __shfl_xor(ox.w, 8, 64);
    float4 hm = make_float4(0.5f * (ox.x + oo.x), 0.5f * (ox.y + oo.y),
                            0.5f * (ox.z + oo.z), 0.5f * (ox.w + oo.w));

    // residual + LayerNorm + leaky(0.01); reload the tasks_x row here
    float4 r0 = tp[0], r1 = tp[1], r2 = tp[2];
    float tf[12] = { r0.x, r0.y, r0.z, r0.w, r1.x, r1.y, r1.z, r1.w,
                     r2.x, r2.y, r2.z, r2.w };
    int u8 = u & 7;
    float4 bias4 = ((const float4*)bias)[u8];
    float4 v4 = make_float4(hm.x + bias4.x, hm.y + bias4.y,
                            hm.z + bias4.z, hm.w + bias4.w);
#pragma unroll
    for (int k = 0; k < 12; ++k) {
        float4 w = ((const float4*)(Wres + k * 32))[u8];
        v4.x = fmaf(tf[k], w.x, v4.x);
        v4.y = fmaf(tf[k], w.y, v4.y);
        v4.z = fmaf(tf[k], w.z, v4.z);
        v4.w = fmaf(tf[k], w.w, v4.w);
    }
    float loc = v4.x + v4.y + v4.z + v4.w;
    float mean = sum16(loc) * (1.0f / 64.0f);    // lanes u and u^8 duplicate
    float4 dd = make_float4(v4.x - mean, v4.y - mean, v4.z - mean, v4.w - mean);
    float q2l = dd.x * dd.x + dd.y * dd.y + dd.z * dd.z + dd.w * dd.w;
    float var = sum16(q2l) * (1.0f / 64.0f);
    float rs = rsqrtf(var + 1e-5f);
    float4 g4 = ((const float4*)g)[u8];
    float4 b4 = ((const float4*)bln)[u8];
    float4 y;
    y.x = dd.x * rs * g4.x + b4.x;  y.x = (y.x >= 0.f ? y.x : 0.01f * y.x);
    y.y = dd.y * rs * g4.y + b4.y;  y.y = (y.y >= 0.f ? y.y : 0.01f * y.y);
    y.z = dd.z * rs * g4.z + b4.z;  y.z = (y.z >= 0.f ? y.z : 0.01f * y.z);
    y.w = dd.w * rs * g4.w + b4.w;  y.w = (y.w >= 0.f ? y.w : 0.01f * y.w);
    if (u < 8) *((float4*)(out + (size_t)t * 32 + 4 * u8)) = y;
}

// ---------------------------------------------------------------------------
// pool: per-(graph,chunk) partial sums, no atomics, no memset needed.
// ---------------------------------------------------------------------------
__global__ void pool_kernel(const float* __restrict__ tx, const float* __restrict__ dft,
                            const float* __restrict__ tft, float* __restrict__ glob16) {
    int g = blockIdx.x >> 4;
    int ch = blockIdx.x & 15;
    int j = threadIdx.x;
    if (j >= EMB) return;
    int base = g * TPER + ch * 64;
    float s = 0.0f;
    for (int t = 0; t < 64; ++t) {
        int task = base + t;
        float v;
        if (j < 12)      v = tx[(size_t)task * 12 + j];
        else if (j < 44) v = dft[(size_t)task * 32 + (j - 12)];
        else             v = tft[(size_t)task * 32 + (j - 44)];
        s += v;
    }
    glob16[(size_t)blockIdx.x * EMB + j] = s;
}

// ---------------------------------------------------------------------------
// head: per-graph cand/glob/dev concat -> [200] @ h1_W -> LN -> leaky -> h2
// ---------------------------------------------------------------------------
__global__ void head_kernel(const float* __restrict__ tx, const float* __restrict__ dft,
                            const float* __restrict__ tft, const float* __restrict__ glob16,
                            const float* __restrict__ devx, const float* __restrict__ counts,
                            const int* __restrict__ ptrv,
                            const float* __restrict__ h1_W, const float* __restrict__ h1_b,
                            const float* __restrict__ hln_g, const float* __restrict__ hln_b,
                            const float* __restrict__ h2_W, const float* __restrict__ h2_b,
                            float* __restrict__ out) {
    __shared__ float xs[HEAD_IN];
    __shared__ float ys[32];
    int b = blockIdx.x;
    int l = threadIdx.x; // 64 threads
    int p = ptrv[b];
    float inv = 1.0f / fmaxf(counts[b], 1.0f);
    for (int j = l; j < HEAD_IN; j += 64) {
        float v;
        if (j < 12)       v = tx[(size_t)p * 12 + j];
        else if (j < 44)  v = dft[(size_t)p * 32 + (j - 12)];
        else if (j < 76)  v = tft[(size_t)p * 32 + (j - 44)];
        else if (j < 152) {
            float s = 0.f;
#pragma unroll
            for (int c = 0; c < 16; ++c)
                s += glob16[(size_t)(b * 16 + c) * EMB + (j - 76)];
            v = s * inv;
        }
        else              v = devx[b * (NDEV * DEV_D) + (j - 152)];
        xs[j] = v;
    }
    __syncthreads();
    if (l < 32) {
        float h = h1_b[l];
        for (int k = 0; k < HEAD_IN; ++k)
            h += xs[k] * h1_W[k * 32 + l];
        float s = h;
#pragma unroll
        for (int off = 16; off; off >>= 1) s += __shfl_xor(s, off, 64);
        float mean = s * (1.0f / 32.0f);
        float dd = h - mean;
        float q = dd * dd;
#pragma unroll
        for (int off = 16; off; off >>= 1) q += __shfl_xor(q, off, 64);
        float var = q * (1.0f / 32.0f);
        float y = dd * rsqrtf(var + 1e-5f) * hln_g[l] + hln_b[l];
        ys[l] = (y >= 0.0f ? y : 0.01f * y);
    }
    __syncthreads();
    if (l < NDEV - 1) {
        float o = h2_b[l];
        for (int c = 0; c < 32; ++c)
            o += ys[c] * h2_W[c * 3 + l];
        out[b * (NDEV - 1) + l] = o;
    }
}

// ---------------------------------------------------------------------------
// launch
// ---------------------------------------------------------------------------
extern "C" void kernel_launch(void* const* d_in, const int* in_sizes, int n_in,
                              void* d_out, int out_size, void* d_ws, size_t ws_size,
                              hipStream_t stream) {
    const float* tasks_x   = (const float*)d_in[0];
    const float* data_x    = (const float*)d_in[1];
    const float* devices_x = (const float*)d_in[2];
    const int*   ei_dt     = (const int*)d_in[3];
    const float* ea_dt     = (const float*)d_in[4];
    const int*   ei_tt     = (const int*)d_in[5];
    // d_in[6] = batch (unused: graphs are contiguous TPER chunks)
    const int*   ptrv      = (const int*)d_in[7];
    const float* counts    = (const float*)d_in[8];
    const float* c1_Wl   = (const float*)d_in[9];
    const float* c1_bl   = (const float*)d_in[10];
    const float* c1_Wr   = (const float*)d_in[11];
    const float* c1_br   = (const float*)d_in[12];
    const float* c1_We   = (const float*)d_in[13];
    const float* c1_att  = (const float*)d_in[14];
    const float* c1_Wres = (const float*)d_in[15];
    const float* c1_bias = (const float*)d_in[16];
    const float* c2_Wl   = (const float*)d_in[17];
    const float* c2_bl   = (const float*)d_in[18];
    const float* c2_Wr   = (const float*)d_in[19];
    const float* c2_br   = (const float*)d_in[20];
    const float* c2_att  = (const float*)d_in[21];
    const float* c2_Wres = (const float*)d_in[22];
    const float* c2_bias = (const float*)d_in[23];
    const float* ln1_g = (const float*)d_in[24];
    const float* ln1_b = (const float*)d_in[25];
    const float* ln2_g = (const float*)d_in[26];
    const float* ln2_b = (const float*)d_in[27];
    const float* h1_W  = (const float*)d_in[28];
    const float* h1_b  = (const float*)d_in[29];
    const float* hln_g = (const float*)d_in[30];
    const float* hln_b = (const float*)d_in[31];
    const float* h2_W  = (const float*)d_in[32];
    const float* h2_b  = (const float*)d_in[33];
    float* out = (float*)d_out;

    // workspace layout (~135MB)
    char* ws = (char*)d_ws;
    size_t off = 0;
    auto alloc = [&](size_t bytes) -> void* {
        void* p = (void*)(ws + off);
        off += (bytes + 255) & ~(size_t)255;
        return p;
    };
    int*    cnt     = (int*)alloc((size_t)ND2 * 4);            // 1MB
    int*    bucket  = (int*)alloc((size_t)ND2 * CAP * 4);      // 33.5MB (transposed)
    float4* epk     = (float4*)alloc((size_t)EE * 32);         // 33.5MB
    float*  xlt2    = (float*)alloc((size_t)NTASKS * 64 * 4);  // 33.5MB
    float*  dft     = (float*)alloc((size_t)NTASKS * 32 * 4);  // 16.8MB
    float*  tft     = (float*)alloc((size_t)NTASKS * 32 * 4);  // 16.8MB
    float*  glob16  = (float*)alloc((size_t)NB * 16 * EMB * 4);
    if (off > ws_size) return;

    const int BLK = 256;

    // ---- prep: scatter + conv1 pack + conv2 xl table, co-scheduled ----
    hipMemsetAsync(cnt, 0, (size_t)ND2 * 4, stream);
    prep_kernel<<<SCAT_BLOCKS + PACK_BLOCKS + PROJ_BLOCKS, BLK, 0, stream>>>(
        ei_dt, ei_tt, cnt, bucket, data_x, ea_dt, epk, tasks_x, c2_Wl, c2_bl, xlt2);

    // ---- conv1: data -> tasks (4 dsts/wave) ----
    gat_gather4_kernel<true><<<NTASKS / 16, BLK, 0, stream>>>(
        bucket, cnt, epk, c1_Wl, c1_bl, c1_We, nullptr,
        c1_Wr, c1_br, c1_att, tasks_x, c1_Wres, c1_bias, ln1_g, ln1_b, dft);

    // ---- conv2: tasks -> tasks (4 dsts/wave) ----
    gat_gather4_kernel<false><<<NTASKS / 16, BLK, 0, stream>>>(
        bucket + NTASKS, cnt + NTASKS, nullptr, nullptr, nullptr, nullptr,
        xlt2, c2_Wr, c2_br, c2_att, tasks_x, c2_Wres, c2_bias, ln2_g, ln2_b, tft);

    // ---- pooling + head ----
    pool_kernel<<<NB * 16, 128, 0, stream>>>(tasks_x, dft, tft, glob16);
    head_kernel<<<NB, 64, 0, stream>>>(tasks_x, dft, tft, glob16, devices_x, counts, ptrv,
                                       h1_W, h1_b, hln_g, hln_b, h2_W, h2_b, out);
}